// Round 1
// baseline (745.713 us; speedup 1.0000x reference)
//
#include <hip/hip_runtime.h>
#include <math.h>

// SparseGyroidCovarianceProbe: per-batch 32x1024 window -> center -> row-normalize
// -> 32x32 Gram -> eigenvalues (parallel Jacobi) -> 3 scalars.
// Grid: 32 blocks (one per batch) x 256 threads.

namespace {
constexpr int HID = 1024;
constexpr int SEQ = 4096;
constexpr int START = 2032;   // max(0, 4096/2 - 16)
constexpr int NSWEEP = 8;     // Jacobi sweeps (31 rounds each)

__device__ __forceinline__ void pairpq(int r, int m, int& p, int& q) {
    // Round-robin tournament: round r (0..30), pair m (0..15) of indices 0..31.
    if (m == 0) { p = 31; q = r % 31; }
    else        { p = (r + m) % 31; q = (r + 31 - m) % 31; }
}
}  // namespace

__global__ __launch_bounds__(256, 1)
void gyroid_probe_kernel(const float* __restrict__ h, float* __restrict__ out) {
    const int b = blockIdx.x;
    const int t = threadIdx.x;
    // Window base for this batch; rows are HID floats = 256 float4.
    const float4* __restrict__ base4 =
        (const float4*)(h + ((size_t)b * SEQ + (size_t)START) * (size_t)HID);

    __shared__ float C[32][33];                       // Gram (padded stride 33)
    __shared__ __align__(16) float wcbuf[32][264];    // K-chunk staging (256 + pad 8)
    __shared__ float nsq[32];                         // per-row sum of squares
    __shared__ float inv[32];                         // 1/(norm+eps)
    __shared__ float csb[32];                         // c[0..15], s[16..31]
    __shared__ float diag[32];
    __shared__ float misc[4];                         // trace, e0, e7, e8

    // ---- zero init (d_ws/d_out poisoned; LDS undefined) ----
    for (int i = t; i < 32 * 33; i += 256) (&C[0][0])[i] = 0.0f;
    if (t < 32) nsq[t] = 0.0f;
    if (t < 4)  misc[t] = 0.0f;
    __syncthreads();

    // ---- P1: mean over the 32 window rows, for this thread's 4 dims ----
    float4 sum4 = make_float4(0.f, 0.f, 0.f, 0.f);
    #pragma unroll
    for (int w = 0; w < 32; ++w) {
        float4 x = base4[w * 256 + t];
        sum4.x += x.x; sum4.y += x.y; sum4.z += x.z; sum4.w += x.w;
    }
    const float4 mean4 = make_float4(sum4.x * 0.03125f, sum4.y * 0.03125f,
                                     sum4.z * 0.03125f, sum4.w * 0.03125f);

    // ---- P1b: centered sum-of-squares per row (LDS fp32 atomics, offset to
    //           spread same-address contention across the 32 banks) ----
    #pragma unroll
    for (int wi = 0; wi < 32; ++wi) {
        const int w = (wi + (t & 31)) & 31;
        float4 x = base4[w * 256 + t];
        const float dx = x.x - mean4.x, dy = x.y - mean4.y;
        const float dz = x.z - mean4.z, dw = x.w - mean4.w;
        atomicAdd(&nsq[w], dx * dx + dy * dy + dz * dz + dw * dw);
    }
    __syncthreads();

    // ---- P2: Gram C = Wc * Wc^T, K=1024 in 4 chunks of 256 dims.
    //      Thread split: tile = t&15 -> 8x8 register tile (rows ti+4i, cols tj+4j),
    //      kw = t>>4 -> 16-way K split within a chunk. ----
    const int tile = t & 15, kw = t >> 4;
    const int ti = tile >> 2, tj = tile & 3;
    float acc[8][8];
    #pragma unroll
    for (int i = 0; i < 8; ++i)
        #pragma unroll
        for (int j = 0; j < 8; ++j) acc[i][j] = 0.f;

    for (int g = 0; g < 4; ++g) {
        // Stage chunk g: threads 64g..64g+63 own dims 256g..256g+255.
        if ((t >> 6) == g) {
            const int col = t & 63;  // float4 column within chunk
            #pragma unroll
            for (int w = 0; w < 32; ++w) {
                float4 x = base4[w * 256 + t];  // L2-hot re-read
                float4 wc = make_float4(x.x - mean4.x, x.y - mean4.y,
                                        x.z - mean4.z, x.w - mean4.w);
                *(float4*)&wcbuf[w][col * 4] = wc;
            }
        }
        __syncthreads();
        #pragma unroll
        for (int k4 = 0; k4 < 4; ++k4) {
            const int k = kw * 16 + k4 * 4;
            float4 av[8], bv[8];
            #pragma unroll
            for (int i = 0; i < 8; ++i) av[i] = *(const float4*)&wcbuf[ti + 4 * i][k];
            #pragma unroll
            for (int j = 0; j < 8; ++j) bv[j] = *(const float4*)&wcbuf[tj + 4 * j][k];
            #pragma unroll
            for (int i = 0; i < 8; ++i)
                #pragma unroll
                for (int j = 0; j < 8; ++j)
                    acc[i][j] += av[i].x * bv[j].x + av[i].y * bv[j].y
                               + av[i].z * bv[j].z + av[i].w * bv[j].w;
        }
        __syncthreads();
    }

    // Reduce the 16 K-partials per C entry via LDS atomics.
    #pragma unroll
    for (int i = 0; i < 8; ++i)
        #pragma unroll
        for (int j = 0; j < 8; ++j)
            atomicAdd(&C[ti + 4 * i][tj + 4 * j], acc[i][j]);
    __syncthreads();

    // ---- Scale by 1/((norm_w+eps)(norm_v+eps)); accumulate trace ----
    if (t < 32) inv[t] = 1.0f / (sqrtf(nsq[t]) + 1e-8f);
    __syncthreads();
    for (int i = t; i < 1024; i += 256) {
        const int w = i >> 5, v = i & 31;
        C[w][v] *= inv[w] * inv[v];
    }
    __syncthreads();
    if (t < 32) atomicAdd(&misc[0], C[t][t]);   // trace (similarity-invariant)
    __syncthreads();

    // ---- P3: parallel two-sided Jacobi. 16 disjoint pivot pairs per round;
    //      every thread transforms one 2x2 block of the 16x16 pair partition. ----
    for (int sweep = 0; sweep < NSWEEP; ++sweep) {
        for (int r = 0; r < 31; ++r) {
            if (t < 16) {
                int p, q; pairpq(r, t, p, q);
                const float app = C[p][p], aqq = C[q][q], apq = C[p][q];
                float cc = 1.f, ss = 0.f;
                if (fabsf(apq) > 1e-12f) {
                    const float tau = (aqq - app) / (2.f * apq);
                    float tt = 1.f / (fabsf(tau) + sqrtf(1.f + tau * tau));
                    if (tau < 0.f) tt = -tt;
                    cc = rsqrtf(1.f + tt * tt);
                    ss = tt * cc;
                }
                csb[t] = cc; csb[16 + t] = ss;
            }
            __syncthreads();
            {
                const int u = t >> 4, v = t & 15;
                int pu, qu, pv, qv;
                pairpq(r, u, pu, qu);
                pairpq(r, v, pv, qv);
                const float cu = csb[u], su = csb[16 + u];
                const float cv = csb[v], sv = csb[16 + v];
                const float a = C[pu][pv], bb = C[pu][qv];
                const float d = C[qu][pv], e = C[qu][qv];
                // right rotation (columns pv,qv)
                const float a1 = a * cv - bb * sv, b1 = a * sv + bb * cv;
                const float d1 = d * cv - e * sv,  e1 = d * sv + e * cv;
                // left rotation (rows pu,qu)
                C[pu][pv] = cu * a1 - su * d1;
                C[qu][pv] = su * a1 + cu * d1;
                C[pu][qv] = cu * b1 - su * e1;
                C[qu][qv] = su * b1 + cu * e1;
            }
            __syncthreads();
        }
    }

    // ---- Rank-select e0 (max), e7, e8 from the diagonal ----
    if (t < 32) diag[t] = C[t][t];
    __syncthreads();
    if (t < 32) {
        const float dj = diag[t];
        int rank = 0;
        #pragma unroll
        for (int i = 0; i < 32; ++i) {
            const float di = diag[i];
            rank += (di > dj || (di == dj && i < t)) ? 1 : 0;
        }
        if (rank == 0) misc[1] = dj;
        if (rank == 7) misc[2] = dj;
        if (rank == 8) misc[3] = dj;
    }
    __syncthreads();

    if (t == 0) {
        const float tr = misc[0];
        const float e0 = misc[1], e7 = misc[2], e8 = misc[3];
        const float gap   = e7 - e8;
        const float decay = (e0 - e8) * (1.0f / 9.0f);   // NUM_EIG+1 = 9
        const float lmin  = e8 + 1e-8f;
        const float topo  = fmaxf(gap / (decay + 1e-8f), 0.0f);
        const float geo   = lmin / (tr + 1e-8f);
        const float g     = topo + geo;
        out[b]      = g;     // gcve_scores
        out[32 + b] = 0.0f;  // fracture_scores
        out[64 + b] = g;     // total_pressure
    }
}

extern "C" void kernel_launch(void* const* d_in, const int* in_sizes, int n_in,
                              void* d_out, int out_size, void* d_ws, size_t ws_size,
                              hipStream_t stream) {
    const float* h = (const float*)d_in[0];
    float* out = (float*)d_out;
    gyroid_probe_kernel<<<dim3(32), dim3(256), 0, stream>>>(h, out);
}

// Round 2
// 722.184 us; speedup vs baseline: 1.0326x; 1.0326x over previous
//
#include <hip/hip_runtime.h>
#include <math.h>

// SparseGyroidCovarianceProbe: per-batch 32x1024 window -> center -> row-normalize
// -> 32x32 Gram -> eigenvalues (wave-synchronous parallel Jacobi) -> 3 scalars.
// Grid: 32 blocks (one per batch) x 256 threads. Jacobi runs on wave 0 only,
// with intra-wave LDS fences instead of __syncthreads (no barriers in that
// region, so the divergence is legal).

namespace {
constexpr int SEQ = 4096;
constexpr int START = 2032;   // max(0, 4096/2 - 16)
constexpr int NSWEEP = 5;     // Jacobi sweeps (31 rounds each); 8 gave absmax 0.0

__device__ __forceinline__ void pairpq(int r, int m, int& p, int& q) {
    // Round-robin tournament: round r (0..30), pair m (0..15) of indices 0..31.
    if (m == 0) { p = 31; q = r % 31; }
    else        { p = (r + m) % 31; q = (r + 31 - m) % 31; }
}

// Intra-wave LDS fence: pin program order (memory clobber + wave_barrier) and
// drain LDS (lgkmcnt(0)) so cross-lane LDS RAW within the wave is safe.
__device__ __forceinline__ void wavefence() {
    __asm__ volatile("s_waitcnt lgkmcnt(0)" ::: "memory");
    __builtin_amdgcn_wave_barrier();
}
}  // namespace

__global__ __launch_bounds__(256, 1)
void gyroid_probe_kernel(const float* __restrict__ h, float* __restrict__ out) {
    const int b = blockIdx.x;
    const int t = threadIdx.x;
    const float4* __restrict__ base4 =
        (const float4*)(h + ((size_t)b * SEQ + (size_t)START) * (size_t)1024);

    __shared__ float C[32][33];                       // Gram (padded stride 33)
    __shared__ __align__(16) float wcbuf[32][264];    // K-chunk staging (256 + pad 8)
    __shared__ float inv[32];                         // 1/(norm+eps)
    __shared__ float csb[32];                         // c[0..15], s[16..31]
    __shared__ float diag[32];
    __shared__ float misc[4];                         // trace, e0, e7, e8

    // ---- zero init ----
    for (int i = t; i < 32 * 33; i += 256) (&C[0][0])[i] = 0.0f;
    if (t < 4) misc[t] = 0.0f;

    // ---- single global read: thread t owns float4-column t of all 32 rows ----
    float4 xr[32];
    #pragma unroll
    for (int w = 0; w < 32; ++w) xr[w] = base4[w * 256 + t];
    float4 s4 = make_float4(0.f, 0.f, 0.f, 0.f);
    #pragma unroll
    for (int w = 0; w < 32; ++w) {
        s4.x += xr[w].x; s4.y += xr[w].y; s4.z += xr[w].z; s4.w += xr[w].w;
    }
    const float4 m4 = make_float4(s4.x * 0.03125f, s4.y * 0.03125f,
                                  s4.z * 0.03125f, s4.w * 0.03125f);
    #pragma unroll
    for (int w = 0; w < 32; ++w) {
        xr[w].x -= m4.x; xr[w].y -= m4.y; xr[w].z -= m4.z; xr[w].w -= m4.w;
    }
    __syncthreads();   // C zero-init visible before atomics

    // ---- Gram C = Wc * Wc^T, K=1024 in 4 chunks of 256 dims (staged from regs).
    //      tile = t&15 -> 8x8 register tile (rows ti+4i, cols tj+4j),
    //      kw = t>>4 -> 16-way K split within a chunk. ----
    const int tile = t & 15, kw = t >> 4;
    const int ti = tile >> 2, tj = tile & 3;
    float acc[8][8];
    #pragma unroll
    for (int i = 0; i < 8; ++i)
        #pragma unroll
        for (int j = 0; j < 8; ++j) acc[i][j] = 0.f;

    for (int g = 0; g < 4; ++g) {
        if ((t >> 6) == g) {
            const int col = t & 63;
            #pragma unroll
            for (int w = 0; w < 32; ++w)
                *(float4*)&wcbuf[w][col * 4] = xr[w];
        }
        __syncthreads();
        #pragma unroll
        for (int k4 = 0; k4 < 4; ++k4) {
            const int k = kw * 16 + k4 * 4;
            float4 av[8], bv[8];
            #pragma unroll
            for (int i = 0; i < 8; ++i) av[i] = *(const float4*)&wcbuf[ti + 4 * i][k];
            #pragma unroll
            for (int j = 0; j < 8; ++j) bv[j] = *(const float4*)&wcbuf[tj + 4 * j][k];
            #pragma unroll
            for (int i = 0; i < 8; ++i)
                #pragma unroll
                for (int j = 0; j < 8; ++j)
                    acc[i][j] += av[i].x * bv[j].x + av[i].y * bv[j].y
                               + av[i].z * bv[j].z + av[i].w * bv[j].w;
        }
        __syncthreads();
    }

    #pragma unroll
    for (int i = 0; i < 8; ++i)
        #pragma unroll
        for (int j = 0; j < 8; ++j)
            atomicAdd(&C[ti + 4 * i][tj + 4 * j], acc[i][j]);
    __syncthreads();

    // ---- scale by 1/((||wc_w||+eps)(||wc_v||+eps)); norms from pre-scale diag ----
    if (t < 32) inv[t] = 1.0f / (sqrtf(C[t][t]) + 1e-8f);
    __syncthreads();
    for (int i = t; i < 1024; i += 256) {
        const int w = i >> 5, v = i & 31;
        C[w][v] *= inv[w] * inv[v];
    }
    __syncthreads();
    if (t < 32) atomicAdd(&misc[0], C[t][t]);   // trace (similarity-invariant)
    __syncthreads();                             // last block-wide barrier

    // ---- wave-0-only Jacobi (no __syncthreads below this line) ----
    if (t < 64) {
        const int v = t & 15, u0 = t >> 4;
        for (int sweep = 0; sweep < NSWEEP; ++sweep) {
            for (int r = 0; r < 31; ++r) {
                if (t < 16) {
                    int p, q; pairpq(r, t, p, q);
                    const float app = C[p][p], aqq = C[q][q], apq = C[p][q];
                    float cc = 1.f, ss = 0.f;
                    if (fabsf(apq) > 1e-12f) {
                        const float tau = (aqq - app) / (2.f * apq);
                        float tt = 1.f / (fabsf(tau) + sqrtf(1.f + tau * tau));
                        if (tau < 0.f) tt = -tt;
                        cc = rsqrtf(1.f + tt * tt);
                        ss = tt * cc;
                    }
                    csb[t] = cc; csb[16 + t] = ss;
                }
                wavefence();
                {
                    int pv, qv; pairpq(r, v, pv, qv);
                    const float cv = csb[v], sv = csb[16 + v];
                    #pragma unroll
                    for (int kk = 0; kk < 4; ++kk) {
                        const int u = u0 + 4 * kk;
                        int pu, qu; pairpq(r, u, pu, qu);
                        const float cu = csb[u], su = csb[16 + u];
                        const float a = C[pu][pv], bb = C[pu][qv];
                        const float d = C[qu][pv], e = C[qu][qv];
                        const float a1 = a * cv - bb * sv, b1 = a * sv + bb * cv;
                        const float d1 = d * cv - e * sv,  e1 = d * sv + e * cv;
                        C[pu][pv] = cu * a1 - su * d1;
                        C[qu][pv] = su * a1 + cu * d1;
                        C[pu][qv] = cu * b1 - su * e1;
                        C[qu][qv] = su * b1 + cu * e1;
                    }
                }
                wavefence();
            }
        }

        // ---- rank-select e0, e7, e8 and emit (still wave 0 only) ----
        if (t < 32) diag[t] = C[t][t];
        wavefence();
        if (t < 32) {
            const float dj = diag[t];
            int rank = 0;
            #pragma unroll
            for (int i = 0; i < 32; ++i) {
                const float di = diag[i];
                rank += (di > dj || (di == dj && i < t)) ? 1 : 0;
            }
            if (rank == 0) misc[1] = dj;
            if (rank == 7) misc[2] = dj;
            if (rank == 8) misc[3] = dj;
        }
        wavefence();
        if (t == 0) {
            const float tr = misc[0];
            const float e0 = misc[1], e7 = misc[2], e8 = misc[3];
            const float gap   = e7 - e8;
            const float decay = (e0 - e8) * (1.0f / 9.0f);   // NUM_EIG+1 = 9
            const float lmin  = e8 + 1e-8f;
            const float topo  = fmaxf(gap / (decay + 1e-8f), 0.0f);
            const float geo   = lmin / (tr + 1e-8f);
            const float g     = topo + geo;
            out[b]      = g;     // gcve_scores
            out[32 + b] = 0.0f;  // fracture_scores
            out[64 + b] = g;     // total_pressure
        }
    }
}

extern "C" void kernel_launch(void* const* d_in, const int* in_sizes, int n_in,
                              void* d_out, int out_size, void* d_ws, size_t ws_size,
                              hipStream_t stream) {
    const float* h = (const float*)d_in[0];
    float* out = (float*)d_out;
    gyroid_probe_kernel<<<dim3(32), dim3(256), 0, stream>>>(h, out);
}

// Round 4
// 703.777 us; speedup vs baseline: 1.0596x; 1.0262x over previous
//
#include <hip/hip_runtime.h>
#include <math.h>

// SparseGyroidCovarianceProbe: per-batch 32x1024 window -> center -> row-normalize
// -> 32x32 Gram -> eigenvalues (wave-synchronous parallel Jacobi) -> 3 scalars.
// Grid: 32 blocks (one per batch) x 256 threads. Jacobi on wave 0 only; c/s
// broadcast via __shfl (no LDS round-trip); update-block reads issued before
// the c/s transcendental chain to overlap latency.
// NSWEEP=5: 4 sweeps measurably under-converge (round-3 absmax 0.16 — spectrum
// has adjacent gaps ~0.02, quadratic phase completes on sweep 5; 5 gives 0.0).

namespace {
constexpr int SEQ = 4096;
constexpr int START = 2032;   // max(0, 4096/2 - 16)
constexpr int NSWEEP = 5;

__device__ __forceinline__ void pairpq(int r, int m, int& p, int& q) {
    // Round-robin tournament: round r (0..30), pair m (0..15) of indices 0..31.
    if (m == 0) { p = 31; q = r % 31; }
    else        { p = (r + m) % 31; q = (r + 31 - m) % 31; }
}

// Intra-wave LDS fence: drain LDS and pin program order so cross-lane LDS RAW
// within the wave is safe.
__device__ __forceinline__ void wavefence() {
    __asm__ volatile("s_waitcnt lgkmcnt(0)" ::: "memory");
    __builtin_amdgcn_wave_barrier();
}
}  // namespace

__global__ __launch_bounds__(256, 1)
void gyroid_probe_kernel(const float* __restrict__ h, float* __restrict__ out) {
    const int b = blockIdx.x;
    const int t = threadIdx.x;
    const float4* __restrict__ base4 =
        (const float4*)(h + ((size_t)b * SEQ + (size_t)START) * (size_t)1024);

    __shared__ float C[32][33];                       // Gram (padded stride 33)
    __shared__ __align__(16) float wcbuf[32][264];    // K-chunk staging (256 + pad 8)
    __shared__ float inv[32];                         // 1/(norm+eps)
    __shared__ float diag[32];
    __shared__ float misc[4];                         // trace, e0, e7, e8

    // ---- zero init ----
    for (int i = t; i < 32 * 33; i += 256) (&C[0][0])[i] = 0.0f;
    if (t < 4) misc[t] = 0.0f;

    // ---- single global read: thread t owns float4-column t of all 32 rows ----
    float4 xr[32];
    #pragma unroll
    for (int w = 0; w < 32; ++w) xr[w] = base4[w * 256 + t];
    float4 s4 = make_float4(0.f, 0.f, 0.f, 0.f);
    #pragma unroll
    for (int w = 0; w < 32; ++w) {
        s4.x += xr[w].x; s4.y += xr[w].y; s4.z += xr[w].z; s4.w += xr[w].w;
    }
    const float4 m4 = make_float4(s4.x * 0.03125f, s4.y * 0.03125f,
                                  s4.z * 0.03125f, s4.w * 0.03125f);
    #pragma unroll
    for (int w = 0; w < 32; ++w) {
        xr[w].x -= m4.x; xr[w].y -= m4.y; xr[w].z -= m4.z; xr[w].w -= m4.w;
    }
    __syncthreads();   // C zero-init visible before atomics

    // ---- Gram C = Wc * Wc^T, K=1024 in 4 chunks of 256 dims (staged from regs).
    //      tile = t&15 -> 8x8 register tile (rows ti+4i, cols tj+4j),
    //      kw = t>>4 -> 16-way K split within a chunk. ----
    const int tile = t & 15, kw = t >> 4;
    const int ti = tile >> 2, tj = tile & 3;
    float acc[8][8];
    #pragma unroll
    for (int i = 0; i < 8; ++i)
        #pragma unroll
        for (int j = 0; j < 8; ++j) acc[i][j] = 0.f;

    for (int g = 0; g < 4; ++g) {
        if ((t >> 6) == g) {
            const int col = t & 63;
            #pragma unroll
            for (int w = 0; w < 32; ++w)
                *(float4*)&wcbuf[w][col * 4] = xr[w];
        }
        __syncthreads();
        #pragma unroll
        for (int k4 = 0; k4 < 4; ++k4) {
            const int k = kw * 16 + k4 * 4;
            float4 av[8], bv[8];
            #pragma unroll
            for (int i = 0; i < 8; ++i) av[i] = *(const float4*)&wcbuf[ti + 4 * i][k];
            #pragma unroll
            for (int j = 0; j < 8; ++j) bv[j] = *(const float4*)&wcbuf[tj + 4 * j][k];
            #pragma unroll
            for (int i = 0; i < 8; ++i)
                #pragma unroll
                for (int j = 0; j < 8; ++j)
                    acc[i][j] += av[i].x * bv[j].x + av[i].y * bv[j].y
                               + av[i].z * bv[j].z + av[i].w * bv[j].w;
        }
        __syncthreads();
    }

    #pragma unroll
    for (int i = 0; i < 8; ++i)
        #pragma unroll
        for (int j = 0; j < 8; ++j)
            atomicAdd(&C[ti + 4 * i][tj + 4 * j], acc[i][j]);
    __syncthreads();

    // ---- scale by 1/((||wc_w||+eps)(||wc_v||+eps)); norms from pre-scale diag ----
    if (t < 32) inv[t] = 1.0f / (sqrtf(C[t][t]) + 1e-8f);
    __syncthreads();
    for (int i = t; i < 1024; i += 256) {
        const int w = i >> 5, v = i & 31;
        C[w][v] *= inv[w] * inv[v];
    }
    __syncthreads();
    if (t < 32) atomicAdd(&misc[0], C[t][t]);   // trace (similarity-invariant)
    __syncthreads();                             // last block-wide barrier

    // ---- wave-0-only Jacobi (no __syncthreads below this line) ----
    if (t < 64) {
        const int v = t & 15, u0 = t >> 4;   // column-pair v; row-pair set {u0+4k}
        for (int sweep = 0; sweep < NSWEEP; ++sweep) {
            for (int r = 0; r < 31; ++r) {
                int p, q; pairpq(r, v, p, q);          // this lane's column pair
                // Pivot reads for c/s (this lane computes pair v's rotation).
                const float app = C[p][p], aqq = C[q][q], apq = C[p][q];
                // Update-block reads issued now so latency overlaps the c/s chain.
                int pu[4], qu[4];
                float a[4], bb[4], d[4], e[4];
                #pragma unroll
                for (int kk = 0; kk < 4; ++kk) {
                    pairpq(r, u0 + 4 * kk, pu[kk], qu[kk]);
                    a[kk]  = C[pu[kk]][p]; bb[kk] = C[pu[kk]][q];
                    d[kk]  = C[qu[kk]][p]; e[kk]  = C[qu[kk]][q];
                }
                // c/s for pair v (all 64 lanes compute; lanes sharing v agree).
                float cc = 1.f, ss = 0.f;
                if (fabsf(apq) > 1e-12f) {
                    const float tau = (aqq - app) / (2.f * apq);
                    float tt = 1.f / (fabsf(tau) + sqrtf(1.f + tau * tau));
                    if (tau < 0.f) tt = -tt;
                    cc = rsqrtf(1.f + tt * tt);
                    ss = tt * cc;
                }
                // Row-pair coefficients via in-wave shuffle (lane u computed pair u).
                const float cv = cc, sv = ss;
                float cu[4], su[4];
                #pragma unroll
                for (int kk = 0; kk < 4; ++kk) {
                    cu[kk] = __shfl(cc, u0 + 4 * kk, 64);
                    su[kk] = __shfl(ss, u0 + 4 * kk, 64);
                }
                #pragma unroll
                for (int kk = 0; kk < 4; ++kk) {
                    const float a1 = a[kk] * cv - bb[kk] * sv;
                    const float b1 = a[kk] * sv + bb[kk] * cv;
                    const float d1 = d[kk] * cv - e[kk] * sv;
                    const float e1 = d[kk] * sv + e[kk] * cv;
                    C[pu[kk]][p] = cu[kk] * a1 - su[kk] * d1;
                    C[qu[kk]][p] = su[kk] * a1 + cu[kk] * d1;
                    C[pu[kk]][q] = cu[kk] * b1 - su[kk] * e1;
                    C[qu[kk]][q] = su[kk] * b1 + cu[kk] * e1;
                }
                wavefence();
            }
        }

        // ---- rank-select e0, e7, e8 and emit (still wave 0 only) ----
        if (t < 32) diag[t] = C[t][t];
        wavefence();
        if (t < 32) {
            const float dj = diag[t];
            int rank = 0;
            #pragma unroll
            for (int i = 0; i < 32; ++i) {
                const float di = diag[i];
                rank += (di > dj || (di == dj && i < t)) ? 1 : 0;
            }
            if (rank == 0) misc[1] = dj;
            if (rank == 7) misc[2] = dj;
            if (rank == 8) misc[3] = dj;
        }
        wavefence();
        if (t == 0) {
            const float tr = misc[0];
            const float e0 = misc[1], e7 = misc[2], e8 = misc[3];
            const float gap   = e7 - e8;
            const float decay = (e0 - e8) * (1.0f / 9.0f);   // NUM_EIG+1 = 9
            const float lmin  = e8 + 1e-8f;
            const float topo  = fmaxf(gap / (decay + 1e-8f), 0.0f);
            const float geo   = lmin / (tr + 1e-8f);
            const float g     = topo + geo;
            out[b]      = g;     // gcve_scores
            out[32 + b] = 0.0f;  // fracture_scores
            out[64 + b] = g;     // total_pressure
        }
    }
}

extern "C" void kernel_launch(void* const* d_in, const int* in_sizes, int n_in,
                              void* d_out, int out_size, void* d_ws, size_t ws_size,
                              hipStream_t stream) {
    const float* h = (const float*)d_in[0];
    float* out = (float*)d_out;
    gyroid_probe_kernel<<<dim3(32), dim3(256), 0, stream>>>(h, out);
}